// Round 15
// baseline (414.693 us; speedup 1.0000x reference)
//
#include <hip/hip_runtime.h>
#include <hip/hip_bf16.h>

typedef __bf16 bf16;
typedef __bf16 bf16x4 __attribute__((ext_vector_type(4)));
typedef __bf16 bf16x8 __attribute__((ext_vector_type(8)));
typedef float f32x4 __attribute__((ext_vector_type(4)));
typedef unsigned short ushort8_t __attribute__((ext_vector_type(8)));
typedef unsigned int u32x2 __attribute__((ext_vector_type(2)));

#define GLOAD_LDS16(g, l)                                                      \
    __builtin_amdgcn_global_load_lds(                                          \
        (const __attribute__((address_space(1))) void*)(g),                    \
        (__attribute__((address_space(3))) void*)(l), 16, 0, 0)

#define LDS_ADDR(p) ((unsigned)(uintptr_t)(__attribute__((address_space(3))) void*)(p))

// pinned raw barrier: sched_barrier(0) fences IR motion across it (rule #18/m152)
#define SBAR()                                                                 \
    do {                                                                       \
        __builtin_amdgcn_sched_barrier(0);                                     \
        __builtin_amdgcn_s_barrier();                                          \
        __builtin_amdgcn_sched_barrier(0);                                     \
    } while (0)

// Problem constants
// B=4, S=4096, H=1024, G=256, W=8, CHUNK=1024, NUM_HEADS=4, hd=256
// M = B*S = 16384 rows, NC = 16 chunks

// ---------------- wavelet kernel normalization ----------------
__global__ __launch_bounds__(256) void k_wavelet(const float* __restrict__ mw,
                                                 const float* __restrict__ sc,
                                                 float* __restrict__ kern) {
    int w = blockIdx.x;
    int tid = threadIdx.x;
    float s = 0.f;
    for (int h = tid; h < 1024; h += 256) { float v = mw[w * 1024 + h]; s += v * v; }
#pragma unroll
    for (int xm = 1; xm < 64; xm <<= 1) s += __shfl_xor(s, xm);
    __shared__ float red[4];
    if ((tid & 63) == 0) red[tid >> 6] = s;
    __syncthreads();
    float tot = red[0] + red[1] + red[2] + red[3];
    float inv = 1.f / fmaxf(sqrtf(tot), 1e-12f);
    float sg = 1.f / (1.f + __expf(-sc[w]));
    float m = inv * sg;
    for (int h = tid; h < 1024; h += 256) kern[w * 1024 + h] = mw[w * 1024 + h] * m;
}

// ---------------- fused: coeffs (8 wavelet dots) + mix1 (LN+GELU) per row ----------------
__global__ __launch_bounds__(256) void k_front(const float* __restrict__ x,
                                               const float* __restrict__ kern,
                                               const float* __restrict__ w1,
                                               const float* __restrict__ b1,
                                               const float* __restrict__ lng,
                                               const float* __restrict__ lnb,
                                               bf16* __restrict__ g) {
    __shared__ float kl[8 * 1024];
    int tid = threadIdx.x;
    for (int i = tid; i < 8192; i += 256) kl[i] = kern[i];
    __syncthreads();
    int wid = tid >> 6, lane = tid & 63;
    long row = (long)blockIdx.x * 4 + wid;
    float acc[8] = {0, 0, 0, 0, 0, 0, 0, 0};
    const float* xr = x + row * 1024;
    for (int i = 0; i < 16; i++) {
        float xv = xr[lane + i * 64];
#pragma unroll
        for (int w = 0; w < 8; w++) acc[w] += xv * kl[w * 1024 + lane + i * 64];
    }
#pragma unroll
    for (int xm = 1; xm < 64; xm <<= 1) {
#pragma unroll
        for (int w = 0; w < 8; w++) acc[w] += __shfl_xor(acc[w], xm);
    }
    float h[8];
#pragma unroll
    for (int e = 0; e < 8; e++) {
        int j = lane * 8 + e;
        float a = b1[j];
#pragma unroll
        for (int w = 0; w < 8; w++) a += acc[w] * w1[w * 512 + j];
        h[e] = a;
    }
    float s1 = 0.f, s2 = 0.f;
#pragma unroll
    for (int e = 0; e < 8; e++) { s1 += h[e]; s2 += h[e] * h[e]; }
#pragma unroll
    for (int xm = 1; xm < 64; xm <<= 1) {
        s1 += __shfl_xor(s1, xm);
        s2 += __shfl_xor(s2, xm);
    }
    float mean = s1 * (1.f / 512.f);
    float var = s2 * (1.f / 512.f) - mean * mean;
    float inv = rsqrtf(var + 1e-5f);
    bf16x8 out;
#pragma unroll
    for (int e = 0; e < 8; e++) {
        int j = lane * 8 + e;
        float xn = (h[e] - mean) * inv * lng[j] + lnb[j];
        float ge = 0.5f * xn * (1.f + erff(xn * 0.70710678118654752f));
        out[e] = (bf16)ge;
    }
    *(bf16x8*)&g[row * 512 + lane * 8] = out;
}

// ---------------- coalesced weight transpose: 32x32 LDS tiles, all 6 weights, 1 launch ----------
__global__ __launch_bounds__(256) void k_wtrans_t(const float* __restrict__ w2, const float* __restrict__ wq,
                                                  const float* __restrict__ wk, const float* __restrict__ wv,
                                                  const float* __restrict__ wo, const float* __restrict__ ow,
                                                  bf16* __restrict__ w2t, bf16* __restrict__ wqt,
                                                  bf16* __restrict__ wkt, bf16* __restrict__ wvt,
                                                  bf16* __restrict__ wot, bf16* __restrict__ owt) {
    __shared__ float ld[32][33];
    const int t = blockIdx.x;
    const int tid = threadIdx.x;
    const float* src;
    bf16* dst;
    int K, N, lt;
    if (t < 512)       { src = w2; dst = w2t; K = 512;  N = 1024; lt = t; }
    else if (t < 1536) { src = wq; dst = wqt; K = 1024; N = 1024; lt = t - 512; }
    else if (t < 2560) { src = wk; dst = wkt; K = 1024; N = 1024; lt = t - 1536; }
    else if (t < 3584) { src = wv; dst = wvt; K = 1024; N = 1024; lt = t - 2560; }
    else if (t < 4608) { src = wo; dst = wot; K = 1024; N = 1024; lt = t - 3584; }
    else               { src = ow; dst = owt; K = 1024; N = 256;  lt = t - 4608; }
    int kt, nt_;
    if (t < 4608) { kt = lt >> 5; nt_ = lt & 31; }
    else          { kt = lt >> 3; nt_ = lt & 7; }
    const int k0 = kt << 5, n0 = nt_ << 5;
    const int tx = tid & 31, ty = tid >> 5;
#pragma unroll
    for (int m = 0; m < 4; m++) {
        int r = ty + m * 8;
        ld[r][tx] = src[(long)(k0 + r) * N + n0 + tx];
    }
    __syncthreads();
#pragma unroll
    for (int m = 0; m < 4; m++) {
        int r = ty + m * 8;
        dst[(long)(n0 + r) * K + k0 + tx] = (bf16)ld[tx][r];
    }
}

enum { EPI_BF16 = 0, EPI_BF16_BIAS = 1, EPI_F32_BIAS = 2, EPI_VT = 3, EPI_F32 = 4 };

// ---------------- GEMM 256x256, 8 waves, BK=64, 8-PHASE schedule (T1+T2+T3+T4+T5) ----------------
// verified R10/R12/R14: 460->431->414->408 us path
template <int EPI>
__global__ __launch_bounds__(512, 2) void k_gemm8p(const bf16* __restrict__ A,
                                                   const bf16* __restrict__ Bt,
                                                   const float* __restrict__ bias,
                                                   void* __restrict__ Cout,
                                                   int K, int lda, int ldb, int ldc,
                                                   float scale) {
    __shared__ bf16 As[2 * 2 * 128 * 64];   // [buf][half][128][64] = 64 KB
    __shared__ bf16 Bs[2 * 2 * 128 * 64];   // 64 KB
    const int tid = threadIdx.x;
    const int wid = tid >> 6, lane = tid & 63;
    const int wr = wid >> 2, wc = wid & 3;   // 2x4 wave grid; wave owns 128x64
    const int L = blockIdx.y * 4 + blockIdx.x;
    const int logical = ((L & 7) << 5) + (L >> 3);
    const long m0 = (long)(logical >> 2) * 256, n0 = (long)(logical & 3) * 256;
    f32x4 acc[8][4] = {};
    const int lr = lane & 15, gq = lane >> 4;
    const int l7 = lr & 7;

    const int srow = wid * 8 + (lane >> 3);
    const int sg = (lane & 7) ^ (lane >> 3);
    const bf16* aS = A + (m0 + srow) * lda + sg * 8;
    const bf16* bS = Bt + (n0 + srow) * ldb + sg * 8;

    auto stageA = [&](int t, int h) {
        bf16* d = As + (((t & 1) * 2 + h) * 128) * 64 + wid * 512;
        const long kq = (long)t << 6;
        GLOAD_LDS16(aS + (long)(h * 128) * lda + kq, d);
        GLOAD_LDS16(aS + (long)(h * 128 + 64) * lda + kq, d + 4096);
    };
    auto stageB = [&](int t, int h) {
        bf16* d = Bs + (((t & 1) * 2 + h) * 128) * 64 + wid * 512;
        const long kq = (long)t << 6;
        GLOAD_LDS16(bS + (long)(h * 128) * ldb + kq, d);
        GLOAD_LDS16(bS + (long)(h * 128 + 64) * ldb + kq, d + 4096);
    };

    bf16x8 bfr[4][2];
    auto ldB = [&](int b) {
#pragma unroll
        for (int j = 0; j < 4; j++)
#pragma unroll
            for (int kk = 0; kk < 2; kk++)
                bfr[j][kk] = *(const bf16x8*)&Bs[((b * 2 + (wc >> 1)) * 128 +
                                                 (wc & 1) * 64 + j * 16 + lr) * 64 +
                                                (((kk * 4 + gq) ^ l7) << 3)];
    };

    const int nt = K >> 6;
    const int niter = nt >> 1;

    stageA(0, 0); stageA(0, 1); stageB(0, 0); stageB(0, 1);
    stageB(1, 0); stageB(1, 1);
    asm volatile("s_waitcnt vmcnt(4)" ::: "memory");
    SBAR();

    for (int jit = 0; jit < niter - 1; ++jit) {
        const int T = jit << 1;
#pragma unroll
        for (int tp = 0; tp < 2; ++tp) {
#pragma unroll
            for (int q = 0; q < 4; ++q) {
                bf16x8 af[2][2];
                if (q == 0) ldB(tp);
#pragma unroll
                for (int ii = 0; ii < 2; ii++)
#pragma unroll
                    for (int kk = 0; kk < 2; kk++)
                        af[ii][kk] = *(const bf16x8*)&As[((tp * 2 + wr) * 128 +
                                                         (q * 2 + ii) * 16 + lr) * 64 +
                                                        (((kk * 4 + gq) ^ l7) << 3)];
                if (tp == 0) {
                    if (q == 0) stageA(T + 1, 0);
                    else if (q == 1) stageA(T + 1, 1);
                    else if (q == 2) stageB(T + 2, 0);
                    else stageB(T + 2, 1);
                } else {
                    if (q == 0) stageA(T + 2, 0);
                    else if (q == 1) stageA(T + 2, 1);
                    else if (q == 2) stageB(T + 3, 0);
                    else stageB(T + 3, 1);
                }
                if (q == 3) asm volatile("s_waitcnt vmcnt(4)" ::: "memory");
                SBAR();
                asm volatile("s_waitcnt lgkmcnt(0)" ::: "memory");
                __builtin_amdgcn_s_setprio(1);
#pragma unroll
                for (int ii = 0; ii < 2; ii++)
#pragma unroll
                    for (int j = 0; j < 4; j++) {
                        acc[q * 2 + ii][j] = __builtin_amdgcn_mfma_f32_16x16x32_bf16(
                            af[ii][0], bfr[j][0], acc[q * 2 + ii][j], 0, 0, 0);
                        acc[q * 2 + ii][j] = __builtin_amdgcn_mfma_f32_16x16x32_bf16(
                            af[ii][1], bfr[j][1], acc[q * 2 + ii][j], 0, 0, 0);
                    }
                __builtin_amdgcn_s_setprio(0);
                SBAR();
            }
        }
    }
    {
        const int T = nt - 2;
#pragma unroll
        for (int tp = 0; tp < 2; ++tp) {
#pragma unroll
            for (int q = 0; q < 4; ++q) {
                bf16x8 af[2][2];
                if (q == 0) ldB(tp);
#pragma unroll
                for (int ii = 0; ii < 2; ii++)
#pragma unroll
                    for (int kk = 0; kk < 2; kk++)
                        af[ii][kk] = *(const bf16x8*)&As[((tp * 2 + wr) * 128 +
                                                         (q * 2 + ii) * 16 + lr) * 64 +
                                                        (((kk * 4 + gq) ^ l7) << 3)];
                if (tp == 0 && q == 0) stageA(T + 1, 0);
                if (tp == 0 && q == 1) stageA(T + 1, 1);
                if (tp == 0 && q == 3) asm volatile("s_waitcnt vmcnt(0)" ::: "memory");
                SBAR();
                asm volatile("s_waitcnt lgkmcnt(0)" ::: "memory");
                __builtin_amdgcn_s_setprio(1);
#pragma unroll
                for (int ii = 0; ii < 2; ii++)
#pragma unroll
                    for (int j = 0; j < 4; j++) {
                        acc[q * 2 + ii][j] = __builtin_amdgcn_mfma_f32_16x16x32_bf16(
                            af[ii][0], bfr[j][0], acc[q * 2 + ii][j], 0, 0, 0);
                        acc[q * 2 + ii][j] = __builtin_amdgcn_mfma_f32_16x16x32_bf16(
                            af[ii][1], bfr[j][1], acc[q * 2 + ii][j], 0, 0, 0);
                    }
                __builtin_amdgcn_s_setprio(0);
                SBAR();
            }
        }
    }

    const int r0 = (lane >> 4) << 2;
#pragma unroll
    for (int i = 0; i < 8; i++) {
#pragma unroll
        for (int j = 0; j < 4; j++) {
#pragma unroll
            for (int e = 0; e < 4; e++) {
                long m = m0 + wr * 128 + i * 16 + r0 + e;
                long n = n0 + wc * 64 + j * 16 + lr;
                float v = acc[i][j][e] * scale;
                if constexpr (EPI == EPI_BF16_BIAS || EPI == EPI_F32_BIAS) v += bias[n];
                if constexpr (EPI == EPI_F32_BIAS || EPI == EPI_F32) {
                    ((float*)Cout)[m * ldc + n] = v;
                } else if constexpr (EPI == EPI_VT) {
                    long c = m >> 10, s = m & 1023, h = n >> 8, d = n & 255;
                    ((bf16*)Cout)[(((c << 2) + h) << 18) + (d << 10) + s] = (bf16)v;
                } else {
                    ((bf16*)Cout)[m * ldc + n] = (bf16)v;
                }
            }
        }
    }
}

// ---------------- GEMM 128x128 (m97 structure) — for the N=256 final GEMM ----------------
template <int EPI>
__global__ __launch_bounds__(256) void k_gemm(const bf16* __restrict__ A,
                                              const bf16* __restrict__ Bt,
                                              const float* __restrict__ bias,
                                              void* __restrict__ Cout,
                                              int M, int N, int K,
                                              int lda, int ldb, int ldc, float scale) {
    __shared__ bf16 As[128 * 32];
    __shared__ bf16 Bs[128 * 32];
    int tid = threadIdx.x;
    int wid = tid >> 6, lane = tid & 63;
    int wr = wid >> 1, wc = wid & 1;
    const int L = blockIdx.y * 2 + blockIdx.x;
    const int logical = ((L & 7) << 5) + (L >> 3);
    long m0 = (long)(logical >> 1) * 128, n0 = (long)(logical & 1) * 128;
    f32x4 acc[4][4] = {};
    const int lr = lane & 15, ko = (lane >> 4) << 3;

    const int srow = wid * 32 + (lane >> 2);
    const int scol = (lane & 3) << 3;
    const bf16* a0 = A + (m0 + srow) * lda + scol;
    const bf16* a1 = A + (m0 + srow + 16) * lda + scol;
    const bf16* b0 = Bt + (n0 + srow) * ldb + scol;
    const bf16* b1 = Bt + (n0 + srow + 16) * ldb + scol;
    bf16* la0 = As + wid * 1024;
    bf16* la1 = As + wid * 1024 + 512;
    bf16* lb0 = Bs + wid * 1024;
    bf16* lb1 = Bs + wid * 1024 + 512;

    for (int k0 = 0; k0 < K; k0 += 32) {
        GLOAD_LDS16(a0 + k0, la0);
        GLOAD_LDS16(a1 + k0, la1);
        GLOAD_LDS16(b0 + k0, lb0);
        GLOAD_LDS16(b1 + k0, lb1);
        __syncthreads();
        bf16x8 af[4], bfr[4];
#pragma unroll
        for (int i = 0; i < 4; i++)
            af[i] = *(const bf16x8*)&As[(wr * 64 + i * 16 + lr) * 32 + ko];
#pragma unroll
        for (int i = 0; i < 4; i++)
            bfr[i] = *(const bf16x8*)&Bs[(wc * 64 + i * 16 + lr) * 32 + ko];
#pragma unroll
        for (int i = 0; i < 4; i++) {
#pragma unroll
            for (int j = 0; j < 4; j++)
                acc[i][j] = __builtin_amdgcn_mfma_f32_16x16x32_bf16(af[i], bfr[j], acc[i][j], 0, 0, 0);
        }
        __syncthreads();
    }
    const int r0 = (lane >> 4) << 2;
#pragma unroll
    for (int i = 0; i < 4; i++) {
#pragma unroll
        for (int j = 0; j < 4; j++) {
#pragma unroll
            for (int e = 0; e < 4; e++) {
                long m = m0 + wr * 64 + i * 16 + r0 + e;
                long n = n0 + wc * 64 + j * 16 + lr;
                float v = acc[i][j][e] * scale;
                if constexpr (EPI == EPI_BF16_BIAS || EPI == EPI_F32_BIAS) v += bias[n];
                if constexpr (EPI == EPI_F32_BIAS || EPI == EPI_F32) {
                    ((float*)Cout)[m * ldc + n] = v;
                } else {
                    ((bf16*)Cout)[m * ldc + n] = (bf16)v;
                }
            }
        }
    }
}

// ---------------- flash attention: 8 waves, 128 q-rows/block, KVBLK=64 ----------------
// SINGLE-buffered K and V (80 KB LDS -> 2 blocks/CU, 4 waves/SIMD) with counted-vmcnt
// schedule (T4): per iter {vmcnt(4)+bar -> QK -> bar -> stage K(t+1) -> softmax+P ->
// vmcnt(4)+bar -> PV -> bar -> stage V(t+1)}. Issue groups kept contiguous (4 K then
// 4 V per wave) so the per-wave vmcnt count maps to whole groups. Loads stay in
// flight across barriers; latency hides under the long softmax/PV phases; the
// co-resident 2nd block covers the lgkmcnt serialization stalls.
__global__ __launch_bounds__(512, 2) void k_attn(const bf16* __restrict__ q,
                                                 const bf16* __restrict__ k,
                                                 const bf16* __restrict__ vt,
                                                 bf16* __restrict__ ao) {
    __shared__ __align__(16) bf16 smem[16384 + 16384 + 8192];   // 80 KB exactly
    bf16* Ks = smem;            // [64][256]
    bf16* Vs = smem + 16384;    // [256][64]
    bf16* Ps = smem + 32768;    // [8 waves][64][16]  (PT: k-major, q-minor)
    int tid = threadIdx.x;
    int wid = tid >> 6, lane = tid & 63;
    int c = blockIdx.x, h = blockIdx.y, q0 = blockIdx.z * 128;
    const int lr = lane & 15, gq = lane >> 4, ko = gq << 3;
    const int l7 = lr & 7;

    const int krw = wid * 2 + (lane >> 5);                 // 0..15
    const int kg = (lane & 31) ^ (krw & 7);
    const bf16* ksrc = k + ((long)c << 10) * 1024 + h * 256 + kg * 8;
    const int vrw = wid * 8 + ((lane >> 3) & 7);           // 0..63
    const int vg = (lane & 7) ^ ((lane >> 3) & 7);
    const bf16* vsrc = vt + ((long)(c * 4 + h) << 18) + vg * 8;

    long qrow = ((long)c << 10) + q0 + wid * 16 + lr;
    bf16x8 qf[8];
#pragma unroll
    for (int kk = 0; kk < 8; kk++)
        qf[kk] = *(const bf16x8*)&q[qrow * 1024 + h * 256 + kk * 32 + ko];

    f32x4 oacc[16] = {};
    float m_run[4] = {-1e30f, -1e30f, -1e30f, -1e30f};
    float l_run[4] = {0.f, 0.f, 0.f, 0.f};

    bf16* PT = Ps + (wid << 10);
    const unsigned pva = LDS_ADDR(&PT[(gq << 7) + lr]);

    auto stageK = [&](int t) {
        const long kb = (long)t << 6;
#pragma unroll
        for (int i = 0; i < 4; i++)
            GLOAD_LDS16(ksrc + (kb + i * 16 + krw) * 1024, Ks + i * 4096 + wid * 512);
    };
    auto stageV = [&](int t) {
        const long kb = (long)t << 6;
#pragma unroll
        for (int i = 0; i < 4; i++)
            GLOAD_LDS16(vsrc + (long)(i * 64 + vrw) * 1024 + kb, Vs + i * 4096 + wid * 512);
    };

    // prologue: K(0) group then V(0) group (contiguous issue groups of 4)
    stageK(0);
    stageV(0);
    for (int t = 0; t < 16; t++) {
        // wait K(t): oldest 4 outstanding are K(t)'s; V(t) (and later K(t+1)) stay in flight
        asm volatile("s_waitcnt vmcnt(4)" ::: "memory");
        SBAR();
        f32x4 s[4] = {};
        __builtin_amdgcn_s_setprio(1);
#pragma unroll
        for (int kk = 0; kk < 8; kk++) {
#pragma unroll
            for (int n = 0; n < 4; n++)
                s[n] = __builtin_amdgcn_mfma_f32_16x16x32_bf16(
                    qf[kk],
                    *(const bf16x8*)&Ks[((n * 16 + lr) << 8) + ((((kk << 2) + gq) ^ l7) << 3)],
                    s[n], 0, 0, 0);
        }
        __builtin_amdgcn_s_setprio(0);
        SBAR();                       // all waves done reading Ks
        if (t < 15) stageK(t + 1);    // outstanding: V(t) 4 + K(t+1) 4
        // row max of this tile
        float mx[4];
#pragma unroll
        for (int e = 0; e < 4; e++)
            mx[e] = fmaxf(fmaxf(s[0][e], s[1][e]), fmaxf(s[2][e], s[3][e]));
#pragma unroll
        for (int xm = 1; xm < 16; xm <<= 1) {
#pragma unroll
            for (int e = 0; e < 4; e++) mx[e] = fmaxf(mx[e], __shfl_xor(mx[e], xm));
        }
        // defer-max: rescale only if some row's max grew by > THR
        bool need = (mx[0] > m_run[0] + 8.f) || (mx[1] > m_run[1] + 8.f) ||
                    (mx[2] > m_run[2] + 8.f) || (mx[3] > m_run[3] + 8.f);
        if (__any(need)) {
#pragma unroll
            for (int e = 0; e < 4; e++) {
                float mn = fmaxf(m_run[e], mx[e]);
                float al = __expf(m_run[e] - mn);
                m_run[e] = mn;
                l_run[e] *= al;
#pragma unroll
                for (int f = 0; f < 16; f++) oacc[f][e] *= al;
            }
        }
        float rs[4] = {0.f, 0.f, 0.f, 0.f};
#pragma unroll
        for (int n = 0; n < 4; n++) {
#pragma unroll
            for (int e = 0; e < 4; e++) {
                float p = __expf(s[n][e] - m_run[e]);
                s[n][e] = p;
                rs[e] += p;
            }
        }
#pragma unroll
        for (int xm = 1; xm < 16; xm <<= 1) {
#pragma unroll
            for (int e = 0; e < 4; e++) rs[e] += __shfl_xor(rs[e], xm);
        }
#pragma unroll
        for (int e = 0; e < 4; e++) l_run[e] += rs[e];
        // P -> PT[k][q] (per-wave private; lgkmcnt orders write->read)
#pragma unroll
        for (int n = 0; n < 4; n++) {
            bf16x4 pv = {(bf16)s[n][0], (bf16)s[n][1], (bf16)s[n][2], (bf16)s[n][3]};
            *(bf16x4*)&PT[((n * 16 + lr) << 4) + (gq << 2)] = pv;
        }
        asm volatile("s_waitcnt lgkmcnt(0)" ::: "memory");
        u32x2 t0, t1, t2, t3;
        asm volatile("ds_read_b64_tr_b16 %0, %1" : "=v"(t0) : "v"(pva));
        asm volatile("ds_read_b64_tr_b16 %0, %1 offset:128" : "=v"(t1) : "v"(pva));
        asm volatile("ds_read_b64_tr_b16 %0, %1 offset:1024" : "=v"(t2) : "v"(pva));
        asm volatile("ds_read_b64_tr_b16 %0, %1 offset:1152" : "=v"(t3) : "v"(pva));
        asm volatile("s_waitcnt lgkmcnt(0)" ::: "memory");
        __builtin_amdgcn_sched_barrier(0);
        union { u32x2 u[2]; bf16x8 v; } p0, p1;
        p0.u[0] = t0; p0.u[1] = t1;
        p1.u[0] = t2; p1.u[1] = t3;
        const bf16x8 pf0 = p0.v, pf1 = p1.v;
        // wait V(t): oldest outstanding is V(t) (t<15: K(t+1) stays in flight)
        if (t < 15)
            asm volatile("s_waitcnt vmcnt(4)" ::: "memory");
        else
            asm volatile("s_waitcnt vmcnt(0)" ::: "memory");
        SBAR();
        __builtin_amdgcn_s_setprio(1);
#pragma unroll
        for (int n2 = 0; n2 < 16; n2++) {
            const int vrow = (n2 * 16 + lr) << 6;
            const int vswz = gq ^ l7;
            oacc[n2] = __builtin_amdgcn_mfma_f32_16x16x32_bf16(
                pf0, *(const bf16x8*)&Vs[vrow + (vswz << 3)], oacc[n2], 0, 0, 0);
            oacc[n2] = __builtin_amdgcn_mfma_f32_16x16x32_bf16(
                pf1, *(const bf16x8*)&Vs[vrow + ((vswz ^ 4) << 3)], oacc[n2], 0, 0, 0);
        }
        __builtin_amdgcn_s_setprio(0);
        SBAR();                       // all waves done reading Vs
        if (t < 15) stageV(t + 1);    // outstanding: K(t+1) 4 + V(t+1) 4
    }
#pragma unroll
    for (int n2 = 0; n2 < 16; n2++) {
#pragma unroll
        for (int e = 0; e < 4; e++) {
            long row = ((long)c << 10) + q0 + wid * 16 + (gq << 2) + e;
            long col = ((long)h << 8) + n2 * 16 + lr;
            ao[row * 1024 + col] = (bf16)(oacc[n2][e] / l_run[e]);
        }
    }
}

// ---------------- t = LN(o + mixed) (bf16 in, bf16 out) ----------------
__global__ __launch_bounds__(256) void k_outln(const bf16* __restrict__ o,
                                               const bf16* __restrict__ mixed,
                                               const float* __restrict__ g,
                                               const float* __restrict__ b,
                                               bf16* __restrict__ t) {
    long row = blockIdx.x;
    int tid = threadIdx.x;
    int wid = tid >> 6, lane = tid & 63;
    __shared__ float red1[4], red2[4];
    float x[4];
    const bf16* orow = o + row * 1024;
    const bf16* mrow = mixed + row * 1024;
    bf16x4 ov = *(const bf16x4*)&orow[tid * 4];
    bf16x4 mv = *(const bf16x4*)&mrow[tid * 4];
#pragma unroll
    for (int i = 0; i < 4; i++) x[i] = (float)ov[i] + (float)mv[i];
    float s1 = x[0] + x[1] + x[2] + x[3];
    float s2 = x[0] * x[0] + x[1] * x[1] + x[2] * x[2] + x[3] * x[3];
#pragma unroll
    for (int xm = 1; xm < 64; xm <<= 1) {
        s1 += __shfl_xor(s1, xm);
        s2 += __shfl_xor(s2, xm);
    }
    if (lane == 0) { red1[wid] = s1; red2[wid] = s2; }
    __syncthreads();
    s1 = red1[0] + red1[1] + red1[2] + red1[3];
    s2 = red2[0] + red2[1] + red2[2] + red2[3];
    float mean = s1 * (1.f / 1024.f);
    float var = s2 * (1.f / 1024.f) - mean * mean;
    float inv = rsqrtf(var + 1e-5f);
#pragma unroll
    for (int i = 0; i < 4; i++) {
        int j = tid * 4 + i;
        t[row * 1024 + j] = (bf16)((x[i] - mean) * inv * g[j] + b[j]);
    }
}

extern "C" void kernel_launch(void* const* d_in, const int* in_sizes, int n_in,
                              void* d_out, int out_size, void* d_ws, size_t ws_size,
                              hipStream_t stream) {
    const float* x   = (const float*)d_in[0];
    const float* mw  = (const float*)d_in[1];
    const float* sc  = (const float*)d_in[2];
    const float* w1  = (const float*)d_in[3];
    const float* b1  = (const float*)d_in[4];
    const float* lng1 = (const float*)d_in[5];
    const float* lnb1 = (const float*)d_in[6];
    const float* w2  = (const float*)d_in[7];
    const float* b2  = (const float*)d_in[8];
    const float* wq  = (const float*)d_in[9];
    const float* wk  = (const float*)d_in[10];
    const float* wv  = (const float*)d_in[11];
    const float* wo  = (const float*)d_in[12];
    const float* lng2 = (const float*)d_in[13];
    const float* lnb2 = (const float*)d_in[14];
    const float* ow  = (const float*)d_in[15];
    const float* ob  = (const float*)d_in[16];

    char* p = (char*)d_ws;
    auto take = [&](size_t bytes) {
        char* r = p;
        p += (bytes + 255) & ~(size_t)255;
        return r;
    };
    const size_t M = 16384;
    float* kern   = (float*)take(8 * 1024 * sizeof(float));
    bf16* g       = (bf16*)take(M * 512 * 2);
    bf16* mixed   = (bf16*)take(M * 1024 * 2);
    bf16* qb      = (bf16*)take(M * 1024 * 2 * 2);  // q then k; q region reused as bf16 o later
    bf16* kb2     = qb + M * 1024;
    bf16* obf     = qb;
    bf16* vtb     = (bf16*)take(M * 1024 * 2);      // v transposed per (chunk,head); reused as t later
    bf16* tb      = vtb;
    bf16* aob     = (bf16*)take(M * 1024 * 2);
    bf16* w2t     = (bf16*)take((size_t)1024 * 512 * 2);
    bf16* wqt     = (bf16*)take((size_t)1024 * 1024 * 2);
    bf16* wkt     = (bf16*)take((size_t)1024 * 1024 * 2);
    bf16* wvt     = (bf16*)take((size_t)1024 * 1024 * 2);
    bf16* wot     = (bf16*)take((size_t)1024 * 1024 * 2);
    bf16* owt     = (bf16*)take((size_t)256 * 1024 * 2);

    k_wavelet<<<8, 256, 0, stream>>>(mw, sc, kern);
    k_front<<<4096, 256, 0, stream>>>(x, kern, w1, b1, lng1, lnb1, g);

    k_wtrans_t<<<4864, 256, 0, stream>>>(w2, wq, wk, wv, wo, ow,
                                         w2t, wqt, wkt, wvt, wot, owt);

    // mixed = gelu(hid) @ w2 + b2
    k_gemm8p<EPI_BF16_BIAS><<<dim3(4, 64), 512, 0, stream>>>(
        g, w2t, b2, mixed, 512, 512, 512, 1024, 1.f);
    // q (scaled by hd^-0.5), k, v(transposed layout)
    k_gemm8p<EPI_BF16><<<dim3(4, 64), 512, 0, stream>>>(
        mixed, wqt, nullptr, qb, 1024, 1024, 1024, 1024, 0.0625f);
    k_gemm8p<EPI_BF16><<<dim3(4, 64), 512, 0, stream>>>(
        mixed, wkt, nullptr, kb2, 1024, 1024, 1024, 1024, 1.f);
    k_gemm8p<EPI_VT><<<dim3(4, 64), 512, 0, stream>>>(
        mixed, wvt, nullptr, vtb, 1024, 1024, 1024, 1024, 1.f);
    // attention (8 waves, 128 q-rows per block, KVBLK=64, single-buffer K/V, 2 blocks/CU)
    k_attn<<<dim3(16, 4, 8), 512, 0, stream>>>(qb, kb2, vtb, aob);
    // o = ao @ wo (bf16, overwrites q region)
    k_gemm8p<EPI_BF16><<<dim3(4, 64), 512, 0, stream>>>(
        aob, wot, nullptr, obf, 1024, 1024, 1024, 1024, 1.f);
    // t = LN(o + mixed) (overwrites vt region)
    k_outln<<<16384, 256, 0, stream>>>(obf, mixed, lng2, lnb2, tb);
    // y = t @ out_w + out_b (N=256 -> 128^2 kernel, grid 256 blocks)
    k_gemm<EPI_F32_BIAS><<<dim3(2, 128), 256, 0, stream>>>(
        tb, owt, ob, d_out, 16384, 256, 1024, 1024, 1024, 256, 1.f);
}

// Round 16
// 412.975 us; speedup vs baseline: 1.0042x; 1.0042x over previous
//
#include <hip/hip_runtime.h>
#include <hip/hip_bf16.h>

typedef __bf16 bf16;
typedef __bf16 bf16x4 __attribute__((ext_vector_type(4)));
typedef __bf16 bf16x8 __attribute__((ext_vector_type(8)));
typedef float f32x4 __attribute__((ext_vector_type(4)));
typedef unsigned short ushort8_t __attribute__((ext_vector_type(8)));
typedef unsigned int u32x2 __attribute__((ext_vector_type(2)));

#define GLOAD_LDS16(g, l)                                                      \
    __builtin_amdgcn_global_load_lds(                                          \
        (const __attribute__((address_space(1))) void*)(g),                    \
        (__attribute__((address_space(3))) void*)(l), 16, 0, 0)

#define LDS_ADDR(p) ((unsigned)(uintptr_t)(__attribute__((address_space(3))) void*)(p))

// pinned raw barrier: sched_barrier(0) fences IR motion across it (rule #18/m152)
#define SBAR()                                                                 \
    do {                                                                       \
        __builtin_amdgcn_sched_barrier(0);                                     \
        __builtin_amdgcn_s_barrier();                                          \
        __builtin_amdgcn_sched_barrier(0);                                     \
    } while (0)

// Problem constants
// B=4, S=4096, H=1024, G=256, W=8, CHUNK=1024, NUM_HEADS=4, hd=256
// M = B*S = 16384 rows, NC = 16 chunks

// ---------------- wavelet kernel normalization ----------------
__global__ __launch_bounds__(256) void k_wavelet(const float* __restrict__ mw,
                                                 const float* __restrict__ sc,
                                                 float* __restrict__ kern) {
    int w = blockIdx.x;
    int tid = threadIdx.x;
    float s = 0.f;
    for (int h = tid; h < 1024; h += 256) { float v = mw[w * 1024 + h]; s += v * v; }
#pragma unroll
    for (int xm = 1; xm < 64; xm <<= 1) s += __shfl_xor(s, xm);
    __shared__ float red[4];
    if ((tid & 63) == 0) red[tid >> 6] = s;
    __syncthreads();
    float tot = red[0] + red[1] + red[2] + red[3];
    float inv = 1.f / fmaxf(sqrtf(tot), 1e-12f);
    float sg = 1.f / (1.f + __expf(-sc[w]));
    float m = inv * sg;
    for (int h = tid; h < 1024; h += 256) kern[w * 1024 + h] = mw[w * 1024 + h] * m;
}

// ---------------- fused: coeffs (8 wavelet dots) + mix1 (LN+GELU) per row ----------------
__global__ __launch_bounds__(256) void k_front(const float* __restrict__ x,
                                               const float* __restrict__ kern,
                                               const float* __restrict__ w1,
                                               const float* __restrict__ b1,
                                               const float* __restrict__ lng,
                                               const float* __restrict__ lnb,
                                               bf16* __restrict__ g) {
    __shared__ float kl[8 * 1024];
    int tid = threadIdx.x;
    for (int i = tid; i < 8192; i += 256) kl[i] = kern[i];
    __syncthreads();
    int wid = tid >> 6, lane = tid & 63;
    long row = (long)blockIdx.x * 4 + wid;
    float acc[8] = {0, 0, 0, 0, 0, 0, 0, 0};
    const float* xr = x + row * 1024;
    for (int i = 0; i < 16; i++) {
        float xv = xr[lane + i * 64];
#pragma unroll
        for (int w = 0; w < 8; w++) acc[w] += xv * kl[w * 1024 + lane + i * 64];
    }
#pragma unroll
    for (int xm = 1; xm < 64; xm <<= 1) {
#pragma unroll
        for (int w = 0; w < 8; w++) acc[w] += __shfl_xor(acc[w], xm);
    }
    float h[8];
#pragma unroll
    for (int e = 0; e < 8; e++) {
        int j = lane * 8 + e;
        float a = b1[j];
#pragma unroll
        for (int w = 0; w < 8; w++) a += acc[w] * w1[w * 512 + j];
        h[e] = a;
    }
    float s1 = 0.f, s2 = 0.f;
#pragma unroll
    for (int e = 0; e < 8; e++) { s1 += h[e]; s2 += h[e] * h[e]; }
#pragma unroll
    for (int xm = 1; xm < 64; xm <<= 1) {
        s1 += __shfl_xor(s1, xm);
        s2 += __shfl_xor(s2, xm);
    }
    float mean = s1 * (1.f / 512.f);
    float var = s2 * (1.f / 512.f) - mean * mean;
    float inv = rsqrtf(var + 1e-5f);
    bf16x8 out;
#pragma unroll
    for (int e = 0; e < 8; e++) {
        int j = lane * 8 + e;
        float xn = (h[e] - mean) * inv * lng[j] + lnb[j];
        float ge = 0.5f * xn * (1.f + erff(xn * 0.70710678118654752f));
        out[e] = (bf16)ge;
    }
    *(bf16x8*)&g[row * 512 + lane * 8] = out;
}

// ---------------- coalesced weight transpose: 32x32 LDS tiles, all 6 weights, 1 launch ----------
__global__ __launch_bounds__(256) void k_wtrans_t(const float* __restrict__ w2, const float* __restrict__ wq,
                                                  const float* __restrict__ wk, const float* __restrict__ wv,
                                                  const float* __restrict__ wo, const float* __restrict__ ow,
                                                  bf16* __restrict__ w2t, bf16* __restrict__ wqt,
                                                  bf16* __restrict__ wkt, bf16* __restrict__ wvt,
                                                  bf16* __restrict__ wot, bf16* __restrict__ owt) {
    __shared__ float ld[32][33];
    const int t = blockIdx.x;
    const int tid = threadIdx.x;
    const float* src;
    bf16* dst;
    int K, N, lt;
    if (t < 512)       { src = w2; dst = w2t; K = 512;  N = 1024; lt = t; }
    else if (t < 1536) { src = wq; dst = wqt; K = 1024; N = 1024; lt = t - 512; }
    else if (t < 2560) { src = wk; dst = wkt; K = 1024; N = 1024; lt = t - 1536; }
    else if (t < 3584) { src = wv; dst = wvt; K = 1024; N = 1024; lt = t - 2560; }
    else if (t < 4608) { src = wo; dst = wot; K = 1024; N = 1024; lt = t - 3584; }
    else               { src = ow; dst = owt; K = 1024; N = 256;  lt = t - 4608; }
    int kt, nt_;
    if (t < 4608) { kt = lt >> 5; nt_ = lt & 31; }
    else          { kt = lt >> 3; nt_ = lt & 7; }
    const int k0 = kt << 5, n0 = nt_ << 5;
    const int tx = tid & 31, ty = tid >> 5;
#pragma unroll
    for (int m = 0; m < 4; m++) {
        int r = ty + m * 8;
        ld[r][tx] = src[(long)(k0 + r) * N + n0 + tx];
    }
    __syncthreads();
#pragma unroll
    for (int m = 0; m < 4; m++) {
        int r = ty + m * 8;
        dst[(long)(n0 + r) * K + k0 + tx] = (bf16)ld[tx][r];
    }
}

enum { EPI_BF16 = 0, EPI_BF16_BIAS = 1, EPI_F32_BIAS = 2, EPI_VT = 3, EPI_F32 = 4 };

// ---------------- GEMM 256x256, 8 waves, BK=64, 8-PHASE schedule (T1+T2+T3+T4+T5) ----------------
// verified R10/R12/R14: 460->431->414->408 us path
template <int EPI>
__global__ __launch_bounds__(512, 2) void k_gemm8p(const bf16* __restrict__ A,
                                                   const bf16* __restrict__ Bt,
                                                   const float* __restrict__ bias,
                                                   void* __restrict__ Cout,
                                                   int K, int lda, int ldb, int ldc,
                                                   float scale) {
    __shared__ bf16 As[2 * 2 * 128 * 64];   // [buf][half][128][64] = 64 KB
    __shared__ bf16 Bs[2 * 2 * 128 * 64];   // 64 KB
    const int tid = threadIdx.x;
    const int wid = tid >> 6, lane = tid & 63;
    const int wr = wid >> 2, wc = wid & 3;   // 2x4 wave grid; wave owns 128x64
    const int L = blockIdx.y * 4 + blockIdx.x;
    const int logical = ((L & 7) << 5) + (L >> 3);
    const long m0 = (long)(logical >> 2) * 256, n0 = (long)(logical & 3) * 256;
    f32x4 acc[8][4] = {};
    const int lr = lane & 15, gq = lane >> 4;
    const int l7 = lr & 7;

    const int srow = wid * 8 + (lane >> 3);
    const int sg = (lane & 7) ^ (lane >> 3);
    const bf16* aS = A + (m0 + srow) * lda + sg * 8;
    const bf16* bS = Bt + (n0 + srow) * ldb + sg * 8;

    auto stageA = [&](int t, int h) {
        bf16* d = As + (((t & 1) * 2 + h) * 128) * 64 + wid * 512;
        const long kq = (long)t << 6;
        GLOAD_LDS16(aS + (long)(h * 128) * lda + kq, d);
        GLOAD_LDS16(aS + (long)(h * 128 + 64) * lda + kq, d + 4096);
    };
    auto stageB = [&](int t, int h) {
        bf16* d = Bs + (((t & 1) * 2 + h) * 128) * 64 + wid * 512;
        const long kq = (long)t << 6;
        GLOAD_LDS16(bS + (long)(h * 128) * ldb + kq, d);
        GLOAD_LDS16(bS + (long)(h * 128 + 64) * ldb + kq, d + 4096);
    };

    bf16x8 bfr[4][2];
    auto ldB = [&](int b) {
#pragma unroll
        for (int j = 0; j < 4; j++)
#pragma unroll
            for (int kk = 0; kk < 2; kk++)
                bfr[j][kk] = *(const bf16x8*)&Bs[((b * 2 + (wc >> 1)) * 128 +
                                                 (wc & 1) * 64 + j * 16 + lr) * 64 +
                                                (((kk * 4 + gq) ^ l7) << 3)];
    };

    const int nt = K >> 6;
    const int niter = nt >> 1;

    stageA(0, 0); stageA(0, 1); stageB(0, 0); stageB(0, 1);
    stageB(1, 0); stageB(1, 1);
    asm volatile("s_waitcnt vmcnt(4)" ::: "memory");
    SBAR();

    for (int jit = 0; jit < niter - 1; ++jit) {
        const int T = jit << 1;
#pragma unroll
        for (int tp = 0; tp < 2; ++tp) {
#pragma unroll
            for (int q = 0; q < 4; ++q) {
                bf16x8 af[2][2];
                if (q == 0) ldB(tp);
#pragma unroll
                for (int ii = 0; ii < 2; ii++)
#pragma unroll
                    for (int kk = 0; kk < 2; kk++)
                        af[ii][kk] = *(const bf16x8*)&As[((tp * 2 + wr) * 128 +
                                                         (q * 2 + ii) * 16 + lr) * 64 +
                                                        (((kk * 4 + gq) ^ l7) << 3)];
                if (tp == 0) {
                    if (q == 0) stageA(T + 1, 0);
                    else if (q == 1) stageA(T + 1, 1);
                    else if (q == 2) stageB(T + 2, 0);
                    else stageB(T + 2, 1);
                } else {
                    if (q == 0) stageA(T + 2, 0);
                    else if (q == 1) stageA(T + 2, 1);
                    else if (q == 2) stageB(T + 3, 0);
                    else stageB(T + 3, 1);
                }
                if (q == 3) asm volatile("s_waitcnt vmcnt(4)" ::: "memory");
                SBAR();
                asm volatile("s_waitcnt lgkmcnt(0)" ::: "memory");
                __builtin_amdgcn_s_setprio(1);
#pragma unroll
                for (int ii = 0; ii < 2; ii++)
#pragma unroll
                    for (int j = 0; j < 4; j++) {
                        acc[q * 2 + ii][j] = __builtin_amdgcn_mfma_f32_16x16x32_bf16(
                            af[ii][0], bfr[j][0], acc[q * 2 + ii][j], 0, 0, 0);
                        acc[q * 2 + ii][j] = __builtin_amdgcn_mfma_f32_16x16x32_bf16(
                            af[ii][1], bfr[j][1], acc[q * 2 + ii][j], 0, 0, 0);
                    }
                __builtin_amdgcn_s_setprio(0);
                SBAR();
            }
        }
    }
    {
        const int T = nt - 2;
#pragma unroll
        for (int tp = 0; tp < 2; ++tp) {
#pragma unroll
            for (int q = 0; q < 4; ++q) {
                bf16x8 af[2][2];
                if (q == 0) ldB(tp);
#pragma unroll
                for (int ii = 0; ii < 2; ii++)
#pragma unroll
                    for (int kk = 0; kk < 2; kk++)
                        af[ii][kk] = *(const bf16x8*)&As[((tp * 2 + wr) * 128 +
                                                         (q * 2 + ii) * 16 + lr) * 64 +
                                                        (((kk * 4 + gq) ^ l7) << 3)];
                if (tp == 0 && q == 0) stageA(T + 1, 0);
                if (tp == 0 && q == 1) stageA(T + 1, 1);
                if (tp == 0 && q == 3) asm volatile("s_waitcnt vmcnt(0)" ::: "memory");
                SBAR();
                asm volatile("s_waitcnt lgkmcnt(0)" ::: "memory");
                __builtin_amdgcn_s_setprio(1);
#pragma unroll
                for (int ii = 0; ii < 2; ii++)
#pragma unroll
                    for (int j = 0; j < 4; j++) {
                        acc[q * 2 + ii][j] = __builtin_amdgcn_mfma_f32_16x16x32_bf16(
                            af[ii][0], bfr[j][0], acc[q * 2 + ii][j], 0, 0, 0);
                        acc[q * 2 + ii][j] = __builtin_amdgcn_mfma_f32_16x16x32_bf16(
                            af[ii][1], bfr[j][1], acc[q * 2 + ii][j], 0, 0, 0);
                    }
                __builtin_amdgcn_s_setprio(0);
                SBAR();
            }
        }
    }

    const int r0 = (lane >> 4) << 2;
#pragma unroll
    for (int i = 0; i < 8; i++) {
#pragma unroll
        for (int j = 0; j < 4; j++) {
#pragma unroll
            for (int e = 0; e < 4; e++) {
                long m = m0 + wr * 128 + i * 16 + r0 + e;
                long n = n0 + wc * 64 + j * 16 + lr;
                float v = acc[i][j][e] * scale;
                if constexpr (EPI == EPI_BF16_BIAS || EPI == EPI_F32_BIAS) v += bias[n];
                if constexpr (EPI == EPI_F32_BIAS || EPI == EPI_F32) {
                    ((float*)Cout)[m * ldc + n] = v;
                } else if constexpr (EPI == EPI_VT) {
                    long c = m >> 10, s = m & 1023, h = n >> 8, d = n & 255;
                    ((bf16*)Cout)[(((c << 2) + h) << 18) + (d << 10) + s] = (bf16)v;
                } else {
                    ((bf16*)Cout)[m * ldc + n] = (bf16)v;
                }
            }
        }
    }
}

// ---------------- GEMM 128x128 (m97 structure) — for the N=256 final GEMM ----------------
template <int EPI>
__global__ __launch_bounds__(256) void k_gemm(const bf16* __restrict__ A,
                                              const bf16* __restrict__ Bt,
                                              const float* __restrict__ bias,
                                              void* __restrict__ Cout,
                                              int M, int N, int K,
                                              int lda, int ldb, int ldc, float scale) {
    __shared__ bf16 As[128 * 32];
    __shared__ bf16 Bs[128 * 32];
    int tid = threadIdx.x;
    int wid = tid >> 6, lane = tid & 63;
    int wr = wid >> 1, wc = wid & 1;
    const int L = blockIdx.y * 2 + blockIdx.x;
    const int logical = ((L & 7) << 5) + (L >> 3);
    long m0 = (long)(logical >> 1) * 128, n0 = (long)(logical & 1) * 128;
    f32x4 acc[4][4] = {};
    const int lr = lane & 15, ko = (lane >> 4) << 3;

    const int srow = wid * 32 + (lane >> 2);
    const int scol = (lane & 3) << 3;
    const bf16* a0 = A + (m0 + srow) * lda + scol;
    const bf16* a1 = A + (m0 + srow + 16) * lda + scol;
    const bf16* b0 = Bt + (n0 + srow) * ldb + scol;
    const bf16* b1 = Bt + (n0 + srow + 16) * ldb + scol;
    bf16* la0 = As + wid * 1024;
    bf16* la1 = As + wid * 1024 + 512;
    bf16* lb0 = Bs + wid * 1024;
    bf16* lb1 = Bs + wid * 1024 + 512;

    for (int k0 = 0; k0 < K; k0 += 32) {
        GLOAD_LDS16(a0 + k0, la0);
        GLOAD_LDS16(a1 + k0, la1);
        GLOAD_LDS16(b0 + k0, lb0);
        GLOAD_LDS16(b1 + k0, lb1);
        __syncthreads();
        bf16x8 af[4], bfr[4];
#pragma unroll
        for (int i = 0; i < 4; i++)
            af[i] = *(const bf16x8*)&As[(wr * 64 + i * 16 + lr) * 32 + ko];
#pragma unroll
        for (int i = 0; i < 4; i++)
            bfr[i] = *(const bf16x8*)&Bs[(wc * 64 + i * 16 + lr) * 32 + ko];
#pragma unroll
        for (int i = 0; i < 4; i++) {
#pragma unroll
            for (int j = 0; j < 4; j++)
                acc[i][j] = __builtin_amdgcn_mfma_f32_16x16x32_bf16(af[i], bfr[j], acc[i][j], 0, 0, 0);
        }
        __syncthreads();
    }
    const int r0 = (lane >> 4) << 2;
#pragma unroll
    for (int i = 0; i < 4; i++) {
#pragma unroll
        for (int j = 0; j < 4; j++) {
#pragma unroll
            for (int e = 0; e < 4; e++) {
                long m = m0 + wr * 64 + i * 16 + r0 + e;
                long n = n0 + wc * 64 + j * 16 + lr;
                float v = acc[i][j][e] * scale;
                if constexpr (EPI == EPI_BF16_BIAS || EPI == EPI_F32_BIAS) v += bias[n];
                if constexpr (EPI == EPI_F32_BIAS || EPI == EPI_F32) {
                    ((float*)Cout)[m * ldc + n] = v;
                } else {
                    ((bf16*)Cout)[m * ldc + n] = (bf16)v;
                }
            }
        }
    }
}

// ---------------- flash attention: 8 waves, 128 q-rows/block, KVBLK=64 ----------------
// 72 KB LDS (proven 2 blocks/CU at 73728 B, R5: occupancy 43.8%): single-buffered
// K and V + counted-vmcnt schedule (R15) + SPLIT P round-trip (1 KB/wave buffer,
// two write/tr-read passes relabeling kv 0..31 and 32..63 into the same slots).
// The co-resident second block hides the lgkmcnt serialization stalls.
__global__ __launch_bounds__(512, 2) void k_attn(const bf16* __restrict__ q,
                                                 const bf16* __restrict__ k,
                                                 const bf16* __restrict__ vt,
                                                 bf16* __restrict__ ao) {
    __shared__ __align__(16) bf16 smem[16384 + 16384 + 4096];   // 72 KB exactly
    bf16* Ks = smem;            // [64][256]
    bf16* Vs = smem + 16384;    // [256][64]
    bf16* Ps = smem + 32768;    // [8 waves][32][16]  (PT half-buffer, 1 KB/wave)
    int tid = threadIdx.x;
    int wid = tid >> 6, lane = tid & 63;
    int c = blockIdx.x, h = blockIdx.y, q0 = blockIdx.z * 128;
    const int lr = lane & 15, gq = lane >> 4, ko = gq << 3;
    const int l7 = lr & 7;

    const int krw = wid * 2 + (lane >> 5);                 // 0..15
    const int kg = (lane & 31) ^ (krw & 7);
    const bf16* ksrc = k + ((long)c << 10) * 1024 + h * 256 + kg * 8;
    const int vrw = wid * 8 + ((lane >> 3) & 7);           // 0..63
    const int vg = (lane & 7) ^ ((lane >> 3) & 7);
    const bf16* vsrc = vt + ((long)(c * 4 + h) << 18) + vg * 8;

    long qrow = ((long)c << 10) + q0 + wid * 16 + lr;
    bf16x8 qf[8];
#pragma unroll
    for (int kk = 0; kk < 8; kk++)
        qf[kk] = *(const bf16x8*)&q[qrow * 1024 + h * 256 + kk * 32 + ko];

    f32x4 oacc[16] = {};
    float m_run[4] = {-1e30f, -1e30f, -1e30f, -1e30f};
    float l_run[4] = {0.f, 0.f, 0.f, 0.f};

    bf16* PT = Ps + (wid << 9);                       // [32][16] = 1 KB per wave
    const unsigned pva = LDS_ADDR(&PT[(gq << 7) + lr]);

    auto stageK = [&](int t) {
        const long kb = (long)t << 6;
#pragma unroll
        for (int i = 0; i < 4; i++)
            GLOAD_LDS16(ksrc + (kb + i * 16 + krw) * 1024, Ks + i * 4096 + wid * 512);
    };
    auto stageV = [&](int t) {
        const long kb = (long)t << 6;
#pragma unroll
        for (int i = 0; i < 4; i++)
            GLOAD_LDS16(vsrc + (long)(i * 64 + vrw) * 1024 + kb, Vs + i * 4096 + wid * 512);
    };

    // prologue: K(0) group then V(0) group (contiguous issue groups of 4)
    stageK(0);
    stageV(0);
    for (int t = 0; t < 16; t++) {
        // wait K(t): oldest 4 outstanding are K(t)'s; V(t)/K(t+1) stay in flight
        asm volatile("s_waitcnt vmcnt(4)" ::: "memory");
        SBAR();
        f32x4 s[4] = {};
        __builtin_amdgcn_s_setprio(1);
#pragma unroll
        for (int kk = 0; kk < 8; kk++) {
#pragma unroll
            for (int n = 0; n < 4; n++)
                s[n] = __builtin_amdgcn_mfma_f32_16x16x32_bf16(
                    qf[kk],
                    *(const bf16x8*)&Ks[((n * 16 + lr) << 8) + ((((kk << 2) + gq) ^ l7) << 3)],
                    s[n], 0, 0, 0);
        }
        __builtin_amdgcn_s_setprio(0);
        SBAR();                       // all waves done reading Ks
        if (t < 15) stageK(t + 1);    // outstanding: V(t) 4 + K(t+1) 4
        // row max of this tile
        float mx[4];
#pragma unroll
        for (int e = 0; e < 4; e++)
            mx[e] = fmaxf(fmaxf(s[0][e], s[1][e]), fmaxf(s[2][e], s[3][e]));
#pragma unroll
        for (int xm = 1; xm < 16; xm <<= 1) {
#pragma unroll
            for (int e = 0; e < 4; e++) mx[e] = fmaxf(mx[e], __shfl_xor(mx[e], xm));
        }
        // defer-max: rescale only if some row's max grew by > THR
        bool need = (mx[0] > m_run[0] + 8.f) || (mx[1] > m_run[1] + 8.f) ||
                    (mx[2] > m_run[2] + 8.f) || (mx[3] > m_run[3] + 8.f);
        if (__any(need)) {
#pragma unroll
            for (int e = 0; e < 4; e++) {
                float mn = fmaxf(m_run[e], mx[e]);
                float al = __expf(m_run[e] - mn);
                m_run[e] = mn;
                l_run[e] *= al;
#pragma unroll
                for (int f = 0; f < 16; f++) oacc[f][e] *= al;
            }
        }
        float rs[4] = {0.f, 0.f, 0.f, 0.f};
#pragma unroll
        for (int n = 0; n < 4; n++) {
#pragma unroll
            for (int e = 0; e < 4; e++) {
                float p = __expf(s[n][e] - m_run[e]);
                s[n][e] = p;
                rs[e] += p;
            }
        }
#pragma unroll
        for (int xm = 1; xm < 16; xm <<= 1) {
#pragma unroll
            for (int e = 0; e < 4; e++) rs[e] += __shfl_xor(rs[e], xm);
        }
#pragma unroll
        for (int e = 0; e < 4; e++) l_run[e] += rs[e];
        // ---- P pass A: kv 0..31 (n = 0,1) ----
#pragma unroll
        for (int n = 0; n < 2; n++) {
            bf16x4 pv = {(bf16)s[n][0], (bf16)s[n][1], (bf16)s[n][2], (bf16)s[n][3]};
            *(bf16x4*)&PT[((n * 16 + lr) << 4) + (gq << 2)] = pv;
        }
        asm volatile("s_waitcnt lgkmcnt(0)" ::: "memory");
        u32x2 t0, t1;
        asm volatile("ds_read_b64_tr_b16 %0, %1" : "=v"(t0) : "v"(pva));
        asm volatile("ds_read_b64_tr_b16 %0, %1 offset:128" : "=v"(t1) : "v"(pva));
        asm volatile("s_waitcnt lgkmcnt(0)" ::: "memory");
        __builtin_amdgcn_sched_barrier(0);
        union { u32x2 u[2]; bf16x8 v; } p0;
        p0.u[0] = t0; p0.u[1] = t1;
        const bf16x8 pf0 = p0.v;
        // wait V(t): oldest outstanding is V(t) (t<15: K(t+1) stays in flight)
        if (t < 15)
            asm volatile("s_waitcnt vmcnt(4)" ::: "memory");
        else
            asm volatile("s_waitcnt vmcnt(0)" ::: "memory");
        SBAR();
        __builtin_amdgcn_s_setprio(1);
#pragma unroll
        for (int n2 = 0; n2 < 16; n2++) {
            const int vrow = (n2 * 16 + lr) << 6;
            const int vswz = gq ^ l7;
            oacc[n2] = __builtin_amdgcn_mfma_f32_16x16x32_bf16(
                pf0, *(const bf16x8*)&Vs[vrow + (vswz << 3)], oacc[n2], 0, 0, 0);
        }
        __builtin_amdgcn_s_setprio(0);
        // ---- P pass B: kv 32..63 (n = 2,3) relabeled into the same 1 KB buffer ----
#pragma unroll
        for (int n = 2; n < 4; n++) {
            bf16x4 pv = {(bf16)s[n][0], (bf16)s[n][1], (bf16)s[n][2], (bf16)s[n][3]};
            *(bf16x4*)&PT[(((n - 2) * 16 + lr) << 4) + (gq << 2)] = pv;
        }
        asm volatile("s_waitcnt lgkmcnt(0)" ::: "memory");
        u32x2 t2, t3;
        asm volatile("ds_read_b64_tr_b16 %0, %1" : "=v"(t2) : "v"(pva));
        asm volatile("ds_read_b64_tr_b16 %0, %1 offset:128" : "=v"(t3) : "v"(pva));
        asm volatile("s_waitcnt lgkmcnt(0)" ::: "memory");
        __builtin_amdgcn_sched_barrier(0);
        union { u32x2 u[2]; bf16x8 v; } p1;
        p1.u[0] = t2; p1.u[1] = t3;
        const bf16x8 pf1 = p1.v;
        __builtin_amdgcn_s_setprio(1);
#pragma unroll
        for (int n2 = 0; n2 < 16; n2++) {
            const int vrow = (n2 * 16 + lr) << 6;
            const int vswz = gq ^ l7;
            oacc[n2] = __builtin_amdgcn_mfma_f32_16x16x32_bf16(
                pf1, *(const bf16x8*)&Vs[vrow + ((vswz ^ 4) << 3)], oacc[n2], 0, 0, 0);
        }
        __builtin_amdgcn_s_setprio(0);
        SBAR();                       // all waves done reading Vs
        if (t < 15) stageV(t + 1);    // outstanding: K(t+1) 4 + V(t+1) 4
    }
#pragma unroll
    for (int n2 = 0; n2 < 16; n2++) {
#pragma unroll
        for (int e = 0; e < 4; e++) {
            long row = ((long)c << 10) + q0 + wid * 16 + (gq << 2) + e;
            long col = ((long)h << 8) + n2 * 16 + lr;
            ao[row * 1024 + col] = (bf16)(oacc[n2][e] / l_run[e]);
        }
    }
}

// ---------------- t = LN(o + mixed) (bf16 in, bf16 out) ----------------
__global__ __launch_bounds__(256) void k_outln(const bf16* __restrict__ o,
                                               const bf16* __restrict__ mixed,
                                               const float* __restrict__ g,
                                               const float* __restrict__ b,
                                               bf16* __restrict__ t) {
    long row = blockIdx.x;
    int tid = threadIdx.x;
    int wid = tid >> 6, lane = tid & 63;
    __shared__ float red1[4], red2[4];
    float x[4];
    const bf16* orow = o + row * 1024;
    const bf16* mrow = mixed + row * 1024;
    bf16x4 ov = *(const bf16x4*)&orow[tid * 4];
    bf16x4 mv = *(const bf16x4*)&mrow[tid * 4];
#pragma unroll
    for (int i = 0; i < 4; i++) x[i] = (float)ov[i] + (float)mv[i];
    float s1 = x[0] + x[1] + x[2] + x[3];
    float s2 = x[0] * x[0] + x[1] * x[1] + x[2] * x[2] + x[3] * x[3];
#pragma unroll
    for (int xm = 1; xm < 64; xm <<= 1) {
        s1 += __shfl_xor(s1, xm);
        s2 += __shfl_xor(s2, xm);
    }
    if (lane == 0) { red1[wid] = s1; red2[wid] = s2; }
    __syncthreads();
    s1 = red1[0] + red1[1] + red1[2] + red1[3];
    s2 = red2[0] + red2[1] + red2[2] + red2[3];
    float mean = s1 * (1.f / 1024.f);
    float var = s2 * (1.f / 1024.f) - mean * mean;
    float inv = rsqrtf(var + 1e-5f);
#pragma unroll
    for (int i = 0; i < 4; i++) {
        int j = tid * 4 + i;
        t[row * 1024 + j] = (bf16)((x[i] - mean) * inv * g[j] + b[j]);
    }
}

extern "C" void kernel_launch(void* const* d_in, const int* in_sizes, int n_in,
                              void* d_out, int out_size, void* d_ws, size_t ws_size,
                              hipStream_t stream) {
    const float* x   = (const float*)d_in[0];
    const float* mw  = (const float*)d_in[1];
    const float* sc  = (const float*)d_in[2];
    const float* w1  = (const float*)d_in[3];
    const float* b1  = (const float*)d_in[4];
    const float* lng1 = (const float*)d_in[5];
    const float* lnb1 = (const float*)d_in[6];
    const float* w2  = (const float*)d_in[7];
    const float* b2  = (const float*)d_in[8];
    const float* wq  = (const float*)d_in[9];
    const float* wk  = (const float*)d_in[10];
    const float* wv  = (const float*)d_in[11];
    const float* wo  = (const float*)d_in[12];
    const float* lng2 = (const float*)d_in[13];
    const float* lnb2 = (const float*)d_in[14];
    const float* ow  = (const float*)d_in[15];
    const float* ob  = (const float*)d_in[16];

    char* p = (char*)d_ws;
    auto take = [&](size_t bytes) {
        char* r = p;
        p += (bytes + 255) & ~(size_t)255;
        return r;
    };
    const size_t M = 16384;
    float* kern   = (float*)take(8 * 1024 * sizeof(float));
    bf16* g       = (bf16*)take(M * 512 * 2);
    bf16* mixed   = (bf16*)take(M * 1024 * 2);
    bf16* qb      = (bf16*)take(M * 1024 * 2 * 2);  // q then k; q region reused as bf16 o later
    bf16* kb2     = qb + M * 1024;
    bf16* obf     = qb;
    bf16* vtb     = (bf16*)take(M * 1024 * 2);      // v transposed per (chunk,head); reused as t later
    bf16* tb      = vtb;
    bf16* aob     = (bf16*)take(M * 1024 * 2);
    bf16* w2t     = (bf16*)take((size_t)1024 * 512 * 2);
    bf16* wqt     = (bf16*)take((size_t)1024 * 1024 * 2);
    bf16* wkt     = (bf16*)take((size_t)1024 * 1024 * 2);
    bf16* wvt     = (bf16*)take((size_t)1024 * 1024 * 2);
    bf16* wot     = (bf16*)take((size_t)1024 * 1024 * 2);
    bf16* owt     = (bf16*)take((size_t)256 * 1024 * 2);

    k_wavelet<<<8, 256, 0, stream>>>(mw, sc, kern);
    k_front<<<4096, 256, 0, stream>>>(x, kern, w1, b1, lng1, lnb1, g);

    k_wtrans_t<<<4864, 256, 0, stream>>>(w2, wq, wk, wv, wo, ow,
                                         w2t, wqt, wkt, wvt, wot, owt);

    // mixed = gelu(hid) @ w2 + b2
    k_gemm8p<EPI_BF16_BIAS><<<dim3(4, 64), 512, 0, stream>>>(
        g, w2t, b2, mixed, 512, 512, 512, 1024, 1.f);
    // q (scaled by hd^-0.5), k, v(transposed layout)
    k_gemm8p<EPI_BF16><<<dim3(4, 64), 512, 0, stream>>>(
        mixed, wqt, nullptr, qb, 1024, 1024, 1024, 1024, 0.0625f);
    k_gemm8p<EPI_BF16><<<dim3(4, 64), 512, 0, stream>>>(
        mixed, wkt, nullptr, kb2, 1024, 1024, 1024, 1024, 1.f);
    k_gemm8p<EPI_VT><<<dim3(4, 64), 512, 0, stream>>>(
        mixed, wvt, nullptr, vtb, 1024, 1024, 1024, 1024, 1.f);
    // attention (8 waves, 128 q-rows per block, KVBLK=64, 72 KB LDS -> 2 blocks/CU)
    k_attn<<<dim3(16, 4, 8), 512, 0, stream>>>(qb, kb2, vtb, aob);
    // o = ao @ wo (bf16, overwrites q region)
    k_gemm8p<EPI_BF16><<<dim3(4, 64), 512, 0, stream>>>(
        aob, wot, nullptr, obf, 1024, 1024, 1024, 1024, 1.f);
    // t = LN(o + mixed) (overwrites vt region)
    k_outln<<<16384, 256, 0, stream>>>(obf, mixed, lng2, lnb2, tb);
    // y = t @ out_w + out_b (N=256 -> 128^2 kernel, grid 256 blocks)
    k_gemm<EPI_F32_BIAS><<<dim3(2, 128), 256, 0, stream>>>(
        tb, owt, ob, d_out, 16384, 256, 1024, 1024, 1024, 256, 1.f);
}

// Round 17
// 407.858 us; speedup vs baseline: 1.0168x; 1.0125x over previous
//
#include <hip/hip_runtime.h>
#include <hip/hip_bf16.h>

typedef __bf16 bf16;
typedef __bf16 bf16x4 __attribute__((ext_vector_type(4)));
typedef __bf16 bf16x8 __attribute__((ext_vector_type(8)));
typedef float f32x4 __attribute__((ext_vector_type(4)));
typedef unsigned short ushort8_t __attribute__((ext_vector_type(8)));
typedef unsigned int u32x2 __attribute__((ext_vector_type(2)));

#define GLOAD_LDS16(g, l)                                                      \
    __builtin_amdgcn_global_load_lds(                                          \
        (const __attribute__((address_space(1))) void*)(g),                    \
        (__attribute__((address_space(3))) void*)(l), 16, 0, 0)

#define LDS_ADDR(p) ((unsigned)(uintptr_t)(__attribute__((address_space(3))) void*)(p))

// pinned raw barrier: sched_barrier(0) fences IR motion across it (rule #18/m152)
#define SBAR()                                                                 \
    do {                                                                       \
        __builtin_amdgcn_sched_barrier(0);                                     \
        __builtin_amdgcn_s_barrier();                                          \
        __builtin_amdgcn_sched_barrier(0);                                     \
    } while (0)

// Problem constants
// B=4, S=4096, H=1024, G=256, W=8, CHUNK=1024, NUM_HEADS=4, hd=256
// M = B*S = 16384 rows, NC = 16 chunks

// ---------------- wavelet kernel normalization ----------------
__global__ __launch_bounds__(256) void k_wavelet(const float* __restrict__ mw,
                                                 const float* __restrict__ sc,
                                                 float* __restrict__ kern) {
    int w = blockIdx.x;
    int tid = threadIdx.x;
    float s = 0.f;
    for (int h = tid; h < 1024; h += 256) { float v = mw[w * 1024 + h]; s += v * v; }
#pragma unroll
    for (int xm = 1; xm < 64; xm <<= 1) s += __shfl_xor(s, xm);
    __shared__ float red[4];
    if ((tid & 63) == 0) red[tid >> 6] = s;
    __syncthreads();
    float tot = red[0] + red[1] + red[2] + red[3];
    float inv = 1.f / fmaxf(sqrtf(tot), 1e-12f);
    float sg = 1.f / (1.f + __expf(-sc[w]));
    float m = inv * sg;
    for (int h = tid; h < 1024; h += 256) kern[w * 1024 + h] = mw[w * 1024 + h] * m;
}

// ---------------- fused: coeffs (8 wavelet dots) + mix1 (LN+GELU) per row ----------------
__global__ __launch_bounds__(256) void k_front(const float* __restrict__ x,
                                               const float* __restrict__ kern,
                                               const float* __restrict__ w1,
                                               const float* __restrict__ b1,
                                               const float* __restrict__ lng,
                                               const float* __restrict__ lnb,
                                               bf16* __restrict__ g) {
    __shared__ float kl[8 * 1024];
    int tid = threadIdx.x;
    for (int i = tid; i < 8192; i += 256) kl[i] = kern[i];
    __syncthreads();
    int wid = tid >> 6, lane = tid & 63;
    long row = (long)blockIdx.x * 4 + wid;
    float acc[8] = {0, 0, 0, 0, 0, 0, 0, 0};
    const float* xr = x + row * 1024;
    for (int i = 0; i < 16; i++) {
        float xv = xr[lane + i * 64];
#pragma unroll
        for (int w = 0; w < 8; w++) acc[w] += xv * kl[w * 1024 + lane + i * 64];
    }
#pragma unroll
    for (int xm = 1; xm < 64; xm <<= 1) {
#pragma unroll
        for (int w = 0; w < 8; w++) acc[w] += __shfl_xor(acc[w], xm);
    }
    float h[8];
#pragma unroll
    for (int e = 0; e < 8; e++) {
        int j = lane * 8 + e;
        float a = b1[j];
#pragma unroll
        for (int w = 0; w < 8; w++) a += acc[w] * w1[w * 512 + j];
        h[e] = a;
    }
    float s1 = 0.f, s2 = 0.f;
#pragma unroll
    for (int e = 0; e < 8; e++) { s1 += h[e]; s2 += h[e] * h[e]; }
#pragma unroll
    for (int xm = 1; xm < 64; xm <<= 1) {
        s1 += __shfl_xor(s1, xm);
        s2 += __shfl_xor(s2, xm);
    }
    float mean = s1 * (1.f / 512.f);
    float var = s2 * (1.f / 512.f) - mean * mean;
    float inv = rsqrtf(var + 1e-5f);
    bf16x8 out;
#pragma unroll
    for (int e = 0; e < 8; e++) {
        int j = lane * 8 + e;
        float xn = (h[e] - mean) * inv * lng[j] + lnb[j];
        float ge = 0.5f * xn * (1.f + erff(xn * 0.70710678118654752f));
        out[e] = (bf16)ge;
    }
    *(bf16x8*)&g[row * 512 + lane * 8] = out;
}

// ---------------- coalesced weight transpose: 32x32 LDS tiles, all 6 weights, 1 launch ----------
__global__ __launch_bounds__(256) void k_wtrans_t(const float* __restrict__ w2, const float* __restrict__ wq,
                                                  const float* __restrict__ wk, const float* __restrict__ wv,
                                                  const float* __restrict__ wo, const float* __restrict__ ow,
                                                  bf16* __restrict__ w2t, bf16* __restrict__ wqt,
                                                  bf16* __restrict__ wkt, bf16* __restrict__ wvt,
                                                  bf16* __restrict__ wot, bf16* __restrict__ owt) {
    __shared__ float ld[32][33];
    const int t = blockIdx.x;
    const int tid = threadIdx.x;
    const float* src;
    bf16* dst;
    int K, N, lt;
    if (t < 512)       { src = w2; dst = w2t; K = 512;  N = 1024; lt = t; }
    else if (t < 1536) { src = wq; dst = wqt; K = 1024; N = 1024; lt = t - 512; }
    else if (t < 2560) { src = wk; dst = wkt; K = 1024; N = 1024; lt = t - 1536; }
    else if (t < 3584) { src = wv; dst = wvt; K = 1024; N = 1024; lt = t - 2560; }
    else if (t < 4608) { src = wo; dst = wot; K = 1024; N = 1024; lt = t - 3584; }
    else               { src = ow; dst = owt; K = 1024; N = 256;  lt = t - 4608; }
    int kt, nt_;
    if (t < 4608) { kt = lt >> 5; nt_ = lt & 31; }
    else          { kt = lt >> 3; nt_ = lt & 7; }
    const int k0 = kt << 5, n0 = nt_ << 5;
    const int tx = tid & 31, ty = tid >> 5;
#pragma unroll
    for (int m = 0; m < 4; m++) {
        int r = ty + m * 8;
        ld[r][tx] = src[(long)(k0 + r) * N + n0 + tx];
    }
    __syncthreads();
#pragma unroll
    for (int m = 0; m < 4; m++) {
        int r = ty + m * 8;
        dst[(long)(n0 + r) * K + k0 + tx] = (bf16)ld[tx][r];
    }
}

enum { EPI_BF16 = 0, EPI_BF16_BIAS = 1, EPI_F32_BIAS = 2, EPI_VT = 3, EPI_F32 = 4 };

// ---------------- GEMM 256x256, 8 waves, BK=64, 8-PHASE schedule (T1+T2+T3+T4+T5) ----------------
// verified R10/R12/R14: 460->431->414->408 us path
template <int EPI>
__global__ __launch_bounds__(512, 2) void k_gemm8p(const bf16* __restrict__ A,
                                                   const bf16* __restrict__ Bt,
                                                   const float* __restrict__ bias,
                                                   void* __restrict__ Cout,
                                                   int K, int lda, int ldb, int ldc,
                                                   float scale) {
    __shared__ bf16 As[2 * 2 * 128 * 64];   // [buf][half][128][64] = 64 KB
    __shared__ bf16 Bs[2 * 2 * 128 * 64];   // 64 KB
    const int tid = threadIdx.x;
    const int wid = tid >> 6, lane = tid & 63;
    const int wr = wid >> 2, wc = wid & 3;   // 2x4 wave grid; wave owns 128x64
    const int L = blockIdx.y * 4 + blockIdx.x;
    const int logical = ((L & 7) << 5) + (L >> 3);
    const long m0 = (long)(logical >> 2) * 256, n0 = (long)(logical & 3) * 256;
    f32x4 acc[8][4] = {};
    const int lr = lane & 15, gq = lane >> 4;
    const int l7 = lr & 7;

    const int srow = wid * 8 + (lane >> 3);
    const int sg = (lane & 7) ^ (lane >> 3);
    const bf16* aS = A + (m0 + srow) * lda + sg * 8;
    const bf16* bS = Bt + (n0 + srow) * ldb + sg * 8;

    auto stageA = [&](int t, int h) {
        bf16* d = As + (((t & 1) * 2 + h) * 128) * 64 + wid * 512;
        const long kq = (long)t << 6;
        GLOAD_LDS16(aS + (long)(h * 128) * lda + kq, d);
        GLOAD_LDS16(aS + (long)(h * 128 + 64) * lda + kq, d + 4096);
    };
    auto stageB = [&](int t, int h) {
        bf16* d = Bs + (((t & 1) * 2 + h) * 128) * 64 + wid * 512;
        const long kq = (long)t << 6;
        GLOAD_LDS16(bS + (long)(h * 128) * ldb + kq, d);
        GLOAD_LDS16(bS + (long)(h * 128 + 64) * ldb + kq, d + 4096);
    };

    bf16x8 bfr[4][2];
    auto ldB = [&](int b) {
#pragma unroll
        for (int j = 0; j < 4; j++)
#pragma unroll
            for (int kk = 0; kk < 2; kk++)
                bfr[j][kk] = *(const bf16x8*)&Bs[((b * 2 + (wc >> 1)) * 128 +
                                                 (wc & 1) * 64 + j * 16 + lr) * 64 +
                                                (((kk * 4 + gq) ^ l7) << 3)];
    };

    const int nt = K >> 6;
    const int niter = nt >> 1;

    stageA(0, 0); stageA(0, 1); stageB(0, 0); stageB(0, 1);
    stageB(1, 0); stageB(1, 1);
    asm volatile("s_waitcnt vmcnt(4)" ::: "memory");
    SBAR();

    for (int jit = 0; jit < niter - 1; ++jit) {
        const int T = jit << 1;
#pragma unroll
        for (int tp = 0; tp < 2; ++tp) {
#pragma unroll
            for (int q = 0; q < 4; ++q) {
                bf16x8 af[2][2];
                if (q == 0) ldB(tp);
#pragma unroll
                for (int ii = 0; ii < 2; ii++)
#pragma unroll
                    for (int kk = 0; kk < 2; kk++)
                        af[ii][kk] = *(const bf16x8*)&As[((tp * 2 + wr) * 128 +
                                                         (q * 2 + ii) * 16 + lr) * 64 +
                                                        (((kk * 4 + gq) ^ l7) << 3)];
                if (tp == 0) {
                    if (q == 0) stageA(T + 1, 0);
                    else if (q == 1) stageA(T + 1, 1);
                    else if (q == 2) stageB(T + 2, 0);
                    else stageB(T + 2, 1);
                } else {
                    if (q == 0) stageA(T + 2, 0);
                    else if (q == 1) stageA(T + 2, 1);
                    else if (q == 2) stageB(T + 3, 0);
                    else stageB(T + 3, 1);
                }
                if (q == 3) asm volatile("s_waitcnt vmcnt(4)" ::: "memory");
                SBAR();
                asm volatile("s_waitcnt lgkmcnt(0)" ::: "memory");
                __builtin_amdgcn_s_setprio(1);
#pragma unroll
                for (int ii = 0; ii < 2; ii++)
#pragma unroll
                    for (int j = 0; j < 4; j++) {
                        acc[q * 2 + ii][j] = __builtin_amdgcn_mfma_f32_16x16x32_bf16(
                            af[ii][0], bfr[j][0], acc[q * 2 + ii][j], 0, 0, 0);
                        acc[q * 2 + ii][j] = __builtin_amdgcn_mfma_f32_16x16x32_bf16(
                            af[ii][1], bfr[j][1], acc[q * 2 + ii][j], 0, 0, 0);
                    }
                __builtin_amdgcn_s_setprio(0);
                SBAR();
            }
        }
    }
    {
        const int T = nt - 2;
#pragma unroll
        for (int tp = 0; tp < 2; ++tp) {
#pragma unroll
            for (int q = 0; q < 4; ++q) {
                bf16x8 af[2][2];
                if (q == 0) ldB(tp);
#pragma unroll
                for (int ii = 0; ii < 2; ii++)
#pragma unroll
                    for (int kk = 0; kk < 2; kk++)
                        af[ii][kk] = *(const bf16x8*)&As[((tp * 2 + wr) * 128 +
                                                         (q * 2 + ii) * 16 + lr) * 64 +
                                                        (((kk * 4 + gq) ^ l7) << 3)];
                if (tp == 0 && q == 0) stageA(T + 1, 0);
                if (tp == 0 && q == 1) stageA(T + 1, 1);
                if (tp == 0 && q == 3) asm volatile("s_waitcnt vmcnt(0)" ::: "memory");
                SBAR();
                asm volatile("s_waitcnt lgkmcnt(0)" ::: "memory");
                __builtin_amdgcn_s_setprio(1);
#pragma unroll
                for (int ii = 0; ii < 2; ii++)
#pragma unroll
                    for (int j = 0; j < 4; j++) {
                        acc[q * 2 + ii][j] = __builtin_amdgcn_mfma_f32_16x16x32_bf16(
                            af[ii][0], bfr[j][0], acc[q * 2 + ii][j], 0, 0, 0);
                        acc[q * 2 + ii][j] = __builtin_amdgcn_mfma_f32_16x16x32_bf16(
                            af[ii][1], bfr[j][1], acc[q * 2 + ii][j], 0, 0, 0);
                    }
                __builtin_amdgcn_s_setprio(0);
                SBAR();
            }
        }
    }

    const int r0 = (lane >> 4) << 2;
#pragma unroll
    for (int i = 0; i < 8; i++) {
#pragma unroll
        for (int j = 0; j < 4; j++) {
#pragma unroll
            for (int e = 0; e < 4; e++) {
                long m = m0 + wr * 128 + i * 16 + r0 + e;
                long n = n0 + wc * 64 + j * 16 + lr;
                float v = acc[i][j][e] * scale;
                if constexpr (EPI == EPI_BF16_BIAS || EPI == EPI_F32_BIAS) v += bias[n];
                if constexpr (EPI == EPI_F32_BIAS || EPI == EPI_F32) {
                    ((float*)Cout)[m * ldc + n] = v;
                } else if constexpr (EPI == EPI_VT) {
                    long c = m >> 10, s = m & 1023, h = n >> 8, d = n & 255;
                    ((bf16*)Cout)[(((c << 2) + h) << 18) + (d << 10) + s] = (bf16)v;
                } else {
                    ((bf16*)Cout)[m * ldc + n] = (bf16)v;
                }
            }
        }
    }
}

// ---------------- GEMM 128x128 (m97 structure) — for the N=256 final GEMM ----------------
template <int EPI>
__global__ __launch_bounds__(256) void k_gemm(const bf16* __restrict__ A,
                                              const bf16* __restrict__ Bt,
                                              const float* __restrict__ bias,
                                              void* __restrict__ Cout,
                                              int M, int N, int K,
                                              int lda, int ldb, int ldc, float scale) {
    __shared__ bf16 As[128 * 32];
    __shared__ bf16 Bs[128 * 32];
    int tid = threadIdx.x;
    int wid = tid >> 6, lane = tid & 63;
    int wr = wid >> 1, wc = wid & 1;
    const int L = blockIdx.y * 2 + blockIdx.x;
    const int logical = ((L & 7) << 5) + (L >> 3);
    long m0 = (long)(logical >> 1) * 128, n0 = (long)(logical & 1) * 128;
    f32x4 acc[4][4] = {};
    const int lr = lane & 15, ko = (lane >> 4) << 3;

    const int srow = wid * 32 + (lane >> 2);
    const int scol = (lane & 3) << 3;
    const bf16* a0 = A + (m0 + srow) * lda + scol;
    const bf16* a1 = A + (m0 + srow + 16) * lda + scol;
    const bf16* b0 = Bt + (n0 + srow) * ldb + scol;
    const bf16* b1 = Bt + (n0 + srow + 16) * ldb + scol;
    bf16* la0 = As + wid * 1024;
    bf16* la1 = As + wid * 1024 + 512;
    bf16* lb0 = Bs + wid * 1024;
    bf16* lb1 = Bs + wid * 1024 + 512;

    for (int k0 = 0; k0 < K; k0 += 32) {
        GLOAD_LDS16(a0 + k0, la0);
        GLOAD_LDS16(a1 + k0, la1);
        GLOAD_LDS16(b0 + k0, lb0);
        GLOAD_LDS16(b1 + k0, lb1);
        __syncthreads();
        bf16x8 af[4], bfr[4];
#pragma unroll
        for (int i = 0; i < 4; i++)
            af[i] = *(const bf16x8*)&As[(wr * 64 + i * 16 + lr) * 32 + ko];
#pragma unroll
        for (int i = 0; i < 4; i++)
            bfr[i] = *(const bf16x8*)&Bs[(wc * 64 + i * 16 + lr) * 32 + ko];
#pragma unroll
        for (int i = 0; i < 4; i++) {
#pragma unroll
            for (int j = 0; j < 4; j++)
                acc[i][j] = __builtin_amdgcn_mfma_f32_16x16x32_bf16(af[i], bfr[j], acc[i][j], 0, 0, 0);
        }
        __syncthreads();
    }
    const int r0 = (lane >> 4) << 2;
#pragma unroll
    for (int i = 0; i < 4; i++) {
#pragma unroll
        for (int j = 0; j < 4; j++) {
#pragma unroll
            for (int e = 0; e < 4; e++) {
                long m = m0 + wr * 64 + i * 16 + r0 + e;
                long n = n0 + wc * 64 + j * 16 + lr;
                float v = acc[i][j][e] * scale;
                if constexpr (EPI == EPI_BF16_BIAS || EPI == EPI_F32_BIAS) v += bias[n];
                if constexpr (EPI == EPI_F32_BIAS || EPI == EPI_F32) {
                    ((float*)Cout)[m * ldc + n] = v;
                } else {
                    ((bf16*)Cout)[m * ldc + n] = (bf16)v;
                }
            }
        }
    }
}

// ---------------- flash attention: 8 waves, 128 q-rows/block, KVBLK=64 (R12/R14 proven) ----------------
// Double-buffered K/V via global_load_lds (pre-swizzled source + swizzled reads);
// P transposed per wave, read back via ds_read_b64_tr_b16; defer-max online softmax.
// Occupancy note: reported VGPR (88) + MFMA accumulators exceeds the 128/wave budget
// for 4 waves/SIMD, so this structure runs 1 block/CU regardless of LDS (R15/R16 probes).
__global__ __launch_bounds__(512, 2) void k_attn(const bf16* __restrict__ q,
                                                 const bf16* __restrict__ k,
                                                 const bf16* __restrict__ vt,
                                                 bf16* __restrict__ ao) {
    __shared__ __align__(16) bf16 smem[2 * 16384 + 2 * 16384 + 8192];
    bf16* Ks = smem;            // [2][64][256]
    bf16* Vs = smem + 32768;    // [2][256][64]
    bf16* Ps = smem + 65536;    // [8 waves][64][16]  (PT: k-major, q-minor)
    int tid = threadIdx.x;
    int wid = tid >> 6, lane = tid & 63;
    int c = blockIdx.x, h = blockIdx.y, q0 = blockIdx.z * 128;
    const int lr = lane & 15, gq = lane >> 4, ko = gq << 3;
    const int l7 = lr & 7;

    const int krw = wid * 2 + (lane >> 5);                 // 0..15
    const int kg = (lane & 31) ^ (krw & 7);
    const bf16* ksrc = k + ((long)c << 10) * 1024 + h * 256 + kg * 8;
    const int vrw = wid * 8 + ((lane >> 3) & 7);           // 0..63
    const int vg = (lane & 7) ^ ((lane >> 3) & 7);
    const bf16* vsrc = vt + ((long)(c * 4 + h) << 18) + vg * 8;

    long qrow = ((long)c << 10) + q0 + wid * 16 + lr;
    bf16x8 qf[8];
#pragma unroll
    for (int kk = 0; kk < 8; kk++)
        qf[kk] = *(const bf16x8*)&q[qrow * 1024 + h * 256 + kk * 32 + ko];

    f32x4 oacc[16] = {};
    float m_run[4] = {-1e30f, -1e30f, -1e30f, -1e30f};
    float l_run[4] = {0.f, 0.f, 0.f, 0.f};

    bf16* PT = Ps + (wid << 10);
    const unsigned pva = LDS_ADDR(&PT[(gq << 7) + lr]);

    // prologue: stage kb=0 into buf 0
#pragma unroll
    for (int i = 0; i < 4; i++) {
        GLOAD_LDS16(ksrc + (long)(i * 16 + krw) * 1024, Ks + i * 4096 + wid * 512);
        GLOAD_LDS16(vsrc + (long)(i * 64 + vrw) * 1024, Vs + i * 4096 + wid * 512);
    }
    __syncthreads();
    int buf = 0;
    for (int t = 0; t < 16; t++) {
        if (t < 15) {
            const int kb = (t + 1) << 6;
            const int ob = (buf ^ 1) << 14;
#pragma unroll
            for (int i = 0; i < 4; i++) {
                GLOAD_LDS16(ksrc + (long)(kb + i * 16 + krw) * 1024, Ks + ob + i * 4096 + wid * 512);
                GLOAD_LDS16(vsrc + (long)(i * 64 + vrw) * 1024 + kb, Vs + ob + i * 4096 + wid * 512);
            }
        }
        const bf16* Kc = Ks + (buf << 14);
        const bf16* Vc = Vs + (buf << 14);
        f32x4 s[4] = {};
        __builtin_amdgcn_s_setprio(1);
#pragma unroll
        for (int kk = 0; kk < 8; kk++) {
#pragma unroll
            for (int n = 0; n < 4; n++)
                s[n] = __builtin_amdgcn_mfma_f32_16x16x32_bf16(
                    qf[kk],
                    *(const bf16x8*)&Kc[((n * 16 + lr) << 8) + ((((kk << 2) + gq) ^ l7) << 3)],
                    s[n], 0, 0, 0);
        }
        __builtin_amdgcn_s_setprio(0);
        // row max of this tile
        float mx[4];
#pragma unroll
        for (int e = 0; e < 4; e++)
            mx[e] = fmaxf(fmaxf(s[0][e], s[1][e]), fmaxf(s[2][e], s[3][e]));
#pragma unroll
        for (int xm = 1; xm < 16; xm <<= 1) {
#pragma unroll
            for (int e = 0; e < 4; e++) mx[e] = fmaxf(mx[e], __shfl_xor(mx[e], xm));
        }
        // defer-max: rescale only if some row's max grew by > THR
        bool need = (mx[0] > m_run[0] + 8.f) || (mx[1] > m_run[1] + 8.f) ||
                    (mx[2] > m_run[2] + 8.f) || (mx[3] > m_run[3] + 8.f);
        if (__any(need)) {
#pragma unroll
            for (int e = 0; e < 4; e++) {
                float mn = fmaxf(m_run[e], mx[e]);
                float al = __expf(m_run[e] - mn);
                m_run[e] = mn;
                l_run[e] *= al;
#pragma unroll
                for (int f = 0; f < 16; f++) oacc[f][e] *= al;
            }
        }
        float rs[4] = {0.f, 0.f, 0.f, 0.f};
#pragma unroll
        for (int n = 0; n < 4; n++) {
#pragma unroll
            for (int e = 0; e < 4; e++) {
                float p = __expf(s[n][e] - m_run[e]);
                s[n][e] = p;
                rs[e] += p;
            }
        }
#pragma unroll
        for (int xm = 1; xm < 16; xm <<= 1) {
#pragma unroll
            for (int e = 0; e < 4; e++) rs[e] += __shfl_xor(rs[e], xm);
        }
#pragma unroll
        for (int e = 0; e < 4; e++) l_run[e] += rs[e];
        // P -> PT[k][q]: lane's 4 q-rows contiguous -> one b64 write per n
#pragma unroll
        for (int n = 0; n < 4; n++) {
            bf16x4 pv = {(bf16)s[n][0], (bf16)s[n][1], (bf16)s[n][2], (bf16)s[n][3]};
            *(bf16x4*)&PT[((n * 16 + lr) << 4) + (gq << 2)] = pv;
        }
        asm volatile("s_waitcnt lgkmcnt(0)" ::: "memory");
        // tr-read A-fragments: pf0 = P[q=lr][k=8gq..8gq+7], pf1 = +32 k
        u32x2 t0, t1, t2, t3;
        asm volatile("ds_read_b64_tr_b16 %0, %1" : "=v"(t0) : "v"(pva));
        asm volatile("ds_read_b64_tr_b16 %0, %1 offset:128" : "=v"(t1) : "v"(pva));
        asm volatile("ds_read_b64_tr_b16 %0, %1 offset:1024" : "=v"(t2) : "v"(pva));
        asm volatile("ds_read_b64_tr_b16 %0, %1 offset:1152" : "=v"(t3) : "v"(pva));
        asm volatile("s_waitcnt lgkmcnt(0)" ::: "memory");
        __builtin_amdgcn_sched_barrier(0);
        union { u32x2 u[2]; bf16x8 v; } p0, p1;
        p0.u[0] = t0; p0.u[1] = t1;
        p1.u[0] = t2; p1.u[1] = t3;
        const bf16x8 pf0 = p0.v, pf1 = p1.v;
        __builtin_amdgcn_s_setprio(1);
#pragma unroll
        for (int n2 = 0; n2 < 16; n2++) {
            const int vrow = (n2 * 16 + lr) << 6;
            const int vswz = gq ^ l7;
            oacc[n2] = __builtin_amdgcn_mfma_f32_16x16x32_bf16(
                pf0, *(const bf16x8*)&Vc[vrow + (vswz << 3)], oacc[n2], 0, 0, 0);
            oacc[n2] = __builtin_amdgcn_mfma_f32_16x16x32_bf16(
                pf1, *(const bf16x8*)&Vc[vrow + ((vswz ^ 4) << 3)], oacc[n2], 0, 0, 0);
        }
        __builtin_amdgcn_s_setprio(0);
        __syncthreads();
        buf ^= 1;
    }
#pragma unroll
    for (int n2 = 0; n2 < 16; n2++) {
#pragma unroll
        for (int e = 0; e < 4; e++) {
            long row = ((long)c << 10) + q0 + wid * 16 + (gq << 2) + e;
            long col = ((long)h << 8) + n2 * 16 + lr;
            ao[row * 1024 + col] = (bf16)(oacc[n2][e] / l_run[e]);
        }
    }
}

// ---------------- t = LN(o + mixed) (bf16 in, bf16 out) ----------------
__global__ __launch_bounds__(256) void k_outln(const bf16* __restrict__ o,
                                               const bf16* __restrict__ mixed,
                                               const float* __restrict__ g,
                                               const float* __restrict__ b,
                                               bf16* __restrict__ t) {
    long row = blockIdx.x;
    int tid = threadIdx.x;
    int wid = tid >> 6, lane = tid & 63;
    __shared__ float red1[4], red2[4];
    float x[4];
    const bf16* orow = o + row * 1024;
    const bf16* mrow = mixed + row * 1024;
    bf16x4 ov = *(const bf16x4*)&orow[tid * 4];
    bf16x4 mv = *(const bf16x4*)&mrow[tid * 4];
#pragma unroll
    for (int i = 0; i < 4; i++) x[i] = (float)ov[i] + (float)mv[i];
    float s1 = x[0] + x[1] + x[2] + x[3];
    float s2 = x[0] * x[0] + x[1] * x[1] + x[2] * x[2] + x[3] * x[3];
#pragma unroll
    for (int xm = 1; xm < 64; xm <<= 1) {
        s1 += __shfl_xor(s1, xm);
        s2 += __shfl_xor(s2, xm);
    }
    if (lane == 0) { red1[wid] = s1; red2[wid] = s2; }
    __syncthreads();
    s1 = red1[0] + red1[1] + red1[2] + red1[3];
    s2 = red2[0] + red2[1] + red2[2] + red2[3];
    float mean = s1 * (1.f / 1024.f);
    float var = s2 * (1.f / 1024.f) - mean * mean;
    float inv = rsqrtf(var + 1e-5f);
#pragma unroll
    for (int i = 0; i < 4; i++) {
        int j = tid * 4 + i;
        t[row * 1024 + j] = (bf16)((x[i] - mean) * inv * g[j] + b[j]);
    }
}

extern "C" void kernel_launch(void* const* d_in, const int* in_sizes, int n_in,
                              void* d_out, int out_size, void* d_ws, size_t ws_size,
                              hipStream_t stream) {
    const float* x   = (const float*)d_in[0];
    const float* mw  = (const float*)d_in[1];
    const float* sc  = (const float*)d_in[2];
    const float* w1  = (const float*)d_in[3];
    const float* b1  = (const float*)d_in[4];
    const float* lng1 = (const float*)d_in[5];
    const float* lnb1 = (const float*)d_in[6];
    const float* w2  = (const float*)d_in[7];
    const float* b2  = (const float*)d_in[8];
    const float* wq  = (const float*)d_in[9];
    const float* wk  = (const float*)d_in[10];
    const float* wv  = (const float*)d_in[11];
    const float* wo  = (const float*)d_in[12];
    const float* lng2 = (const float*)d_in[13];
    const float* lnb2 = (const float*)d_in[14];
    const float* ow  = (const float*)d_in[15];
    const float* ob  = (const float*)d_in[16];

    char* p = (char*)d_ws;
    auto take = [&](size_t bytes) {
        char* r = p;
        p += (bytes + 255) & ~(size_t)255;
        return r;
    };
    const size_t M = 16384;
    float* kern   = (float*)take(8 * 1024 * sizeof(float));
    bf16* g       = (bf16*)take(M * 512 * 2);
    bf16* mixed   = (bf16*)take(M * 1024 * 2);
    bf16* qb      = (bf16*)take(M * 1024 * 2 * 2);  // q then k; q region reused as bf16 o later
    bf16* kb2     = qb + M * 1024;
    bf16* obf     = qb;
    bf16* vtb     = (bf16*)take(M * 1024 * 2);      // v transposed per (chunk,head); reused as t later
    bf16* tb      = vtb;
    bf16* aob     = (bf16*)take(M * 1024 * 2);
    bf16* w2t     = (bf16*)take((size_t)1024 * 512 * 2);
    bf16* wqt     = (bf16*)take((size_t)1024 * 1024 * 2);
    bf16* wkt     = (bf16*)take((size_t)1024 * 1024 * 2);
    bf16* wvt     = (bf16*)take((size_t)1024 * 1024 * 2);
    bf16* wot     = (bf16*)take((size_t)1024 * 1024 * 2);
    bf16* owt     = (bf16*)take((size_t)256 * 1024 * 2);

    k_wavelet<<<8, 256, 0, stream>>>(mw, sc, kern);
    k_front<<<4096, 256, 0, stream>>>(x, kern, w1, b1, lng1, lnb1, g);

    k_wtrans_t<<<4864, 256, 0, stream>>>(w2, wq, wk, wv, wo, ow,
                                         w2t, wqt, wkt, wvt, wot, owt);

    // mixed = gelu(hid) @ w2 + b2
    k_gemm8p<EPI_BF16_BIAS><<<dim3(4, 64), 512, 0, stream>>>(
        g, w2t, b2, mixed, 512, 512, 512, 1024, 1.f);
    // q (scaled by hd^-0.5), k, v(transposed layout)
    k_gemm8p<EPI_BF16><<<dim3(4, 64), 512, 0, stream>>>(
        mixed, wqt, nullptr, qb, 1024, 1024, 1024, 1024, 0.0625f);
    k_gemm8p<EPI_BF16><<<dim3(4, 64), 512, 0, stream>>>(
        mixed, wkt, nullptr, kb2, 1024, 1024, 1024, 1024, 1.f);
    k_gemm8p<EPI_VT><<<dim3(4, 64), 512, 0, stream>>>(
        mixed, wvt, nullptr, vtb, 1024, 1024, 1024, 1024, 1.f);
    // attention (8 waves, 128 q-rows per block, KVBLK=64, double-buffered)
    k_attn<<<dim3(16, 4, 8), 512, 0, stream>>>(qb, kb2, vtb, aob);
    // o = ao @ wo (bf16, overwrites q region)
    k_gemm8p<EPI_BF16><<<dim3(4, 64), 512, 0, stream>>>(
        aob, wot, nullptr, obf, 1024, 1024, 1024, 1024, 1.f);
    // t = LN(o + mixed) (overwrites vt region)
    k_outln<<<16384, 256, 0, stream>>>(obf, mixed, lng2, lnb2, tb);
    // y = t @ out_w + out_b (N=256 -> 128^2 kernel, grid 256 blocks)
    k_gemm<EPI_F32_BIAS><<<dim3(2, 128), 256, 0, stream>>>(
        tb, owt, ob, d_out, 16384, 256, 1024, 1024, 1024, 256, 1.f);
}